// Round 1
// baseline (501.046 us; speedup 1.0000x reference)
//
#include <hip/hip_runtime.h>
#include <hip/hip_bf16.h>

#define LRALPHA 0.2f

typedef __attribute__((ext_vector_type(8))) short frag_ab;   // 8 x bf16
typedef __attribute__((ext_vector_type(4))) float frag_cd;   // 4 x f32
typedef int   iv4 __attribute__((ext_vector_type(4)));
typedef float fv4 __attribute__((ext_vector_type(4)));
typedef unsigned int uv4 __attribute__((ext_vector_type(4)));

static __device__ __forceinline__ unsigned short f2bf(float f) {
  __hip_bfloat16 b = __float2bfloat16(f);
  unsigned short u;
  __builtin_memcpy(&u, &b, 2);
  return u;
}

// ---------------- Kernel A: h = X@W (fp32), s1 = h@a1, s2 = h@a2, hT = bf16(h)^T
__global__ __launch_bounds__(256, 4) void gat_hproj(
    const float* __restrict__ X, const float* __restrict__ W,
    const float* __restrict__ avec,
    float* __restrict__ s1, float* __restrict__ s2,
    unsigned short* __restrict__ hT) {
  const int tid = threadIdx.x;
  const int row0 = blockIdx.x * 16;
  __shared__ __align__(16) float xs[16][256];
  const fv4* xsrc = (const fv4*)(X + (size_t)row0 * 256);
  fv4* xdst = (fv4*)&xs[0][0];
  for (int i = tid; i < 1024; i += 256) xdst[i] = xsrc[i];
  __syncthreads();

  const int c = tid;  // output column 0..255
  float acc[16];
#pragma unroll
  for (int r = 0; r < 16; ++r) acc[r] = 0.f;

  for (int k = 0; k < 256; k += 4) {
    const float w0 = W[(k + 0) * 256 + c];
    const float w1 = W[(k + 1) * 256 + c];
    const float w2 = W[(k + 2) * 256 + c];
    const float w3 = W[(k + 3) * 256 + c];
#pragma unroll
    for (int r = 0; r < 16; ++r) {
      const fv4 xv = *(const fv4*)&xs[r][k];
      acc[r] = fmaf(xv[0], w0, acc[r]);
      acc[r] = fmaf(xv[1], w1, acc[r]);
      acc[r] = fmaf(xv[2], w2, acc[r]);
      acc[r] = fmaf(xv[3], w3, acc[r]);
    }
  }

  // hT (bf16, transposed): thread writes 16 contiguous bf16 in row c
  alignas(16) unsigned short hu[16];
#pragma unroll
  for (int r = 0; r < 16; ++r) hu[r] = f2bf(acc[r]);
  uv4* hdst = (uv4*)(hT + (size_t)c * 8192 + row0);
  hdst[0] = *(const uv4*)&hu[0];
  hdst[1] = *(const uv4*)&hu[8];

  // s1/s2: reduce acc[r]*a over the 256 threads (=columns)
  const float a1c = avec[c];
  const float a2c = avec[256 + c];
  const int lane = tid & 63, wave = tid >> 6;
  __shared__ float r1[4][16], r2[4][16];
#pragma unroll
  for (int r = 0; r < 16; ++r) {
    float v1 = acc[r] * a1c;
    float v2 = acc[r] * a2c;
#pragma unroll
    for (int off = 32; off > 0; off >>= 1) {
      v1 += __shfl_down(v1, off);
      v2 += __shfl_down(v2, off);
    }
    if (lane == 0) { r1[wave][r] = v1; r2[wave][r] = v2; }
  }
  __syncthreads();
  if (tid < 16) {
    s1[row0 + tid] = r1[0][tid] + r1[1][tid] + r1[2][tid] + r1[3][tid];
    s2[row0 + tid] = r2[0][tid] + r2[1][tid] + r2[2][tid] + r2[3][tid];
  }
}

// ---------------- Kernel B: global max of s2 (softmax stabilizer input)
__global__ void gat_s2max(const float* __restrict__ s2, float* __restrict__ s2max) {
  const int tid = threadIdx.x;
  float m = -1e30f;
  for (int i = tid; i < 8192; i += 256) m = fmaxf(m, s2[i]);
#pragma unroll
  for (int off = 32; off > 0; off >>= 1) m = fmaxf(m, __shfl_down(m, off));
  __shared__ float ws[4];
  if ((tid & 63) == 0) ws[tid >> 6] = m;
  __syncthreads();
  if (tid == 0) s2max[0] = fmaxf(fmaxf(ws[0], ws[1]), fmaxf(ws[2], ws[3]));
}

// ---------------- Kernel C: fused masked-softmax numerator + P@h (bf16 MFMA)
// 256 blocks x 512 threads. Block = 64 rows x one j-half (4096 cols).
// Per iter: 64x64 adj tile -> w=exp(lrelu(s1+s2)-m) (bf16) -> LDS A-tile,
// B-fragments read straight from hT (bf16, [f][j] layout, contiguous in j).
__global__ __launch_bounds__(512, 2) void gat_attn(
    const int* __restrict__ adj, const unsigned short* __restrict__ hT,
    const float* __restrict__ s1, const float* __restrict__ s2,
    const float* __restrict__ s2maxp,
    float* __restrict__ pacc, float* __restrict__ pZ) {
  const int bid = blockIdx.x;
  const int x = bid & 7;                       // XCD round-robin slot
  const int ks = x >> 2;                       // j-half pinned per XCD group
  const int rb = ((bid >> 3) << 2) | (x & 3);  // 0..127
  const int row0 = rb * 64;
  const int jlo = ks * 4096;
  const int tid = threadIdx.x;
  const int wave = tid >> 6, lane = tid & 63;
  const int ln16 = lane & 15, quad = lane >> 4;

  __shared__ __align__(16) unsigned short P[64][72];  // 64 rows x 64 k, +8 pad
  __shared__ float Zred[64][8];

  const int r = tid >> 3, cq = tid & 7;  // 64 rows x 8 col-groups of 8
  const float s1r = s1[row0 + r];
  const float s2m = s2maxp[0];
  const float tmv = s1r + s2m;
  const float mr = tmv >= 0.f ? tmv : LRALPHA * tmv;  // lrelu(s1_i + max s2) >= row max

  const int* adjRow = adj + (size_t)(row0 + r) * 8192 + jlo + cq * 8;
  const float* s2p = s2 + jlo + cq * 8;

  frag_cd acc[4][2];
  const frag_cd fz = {0.f, 0.f, 0.f, 0.f};
#pragma unroll
  for (int mi = 0; mi < 4; ++mi)
#pragma unroll
    for (int ni = 0; ni < 2; ++ni) acc[mi][ni] = fz;

  float zloc = 0.f;

  // prefetch iter 0 (adj nontemporal: pure stream, keep hT in L2)
  iv4 pa0 = __builtin_nontemporal_load((const iv4*)(adjRow));
  iv4 pa1 = __builtin_nontemporal_load((const iv4*)(adjRow + 4));
  fv4 pv0 = *(const fv4*)(s2p);
  fv4 pv1 = *(const fv4*)(s2p + 4);

  const int NIT = 4096 / 64;
  for (int jt = 0; jt < NIT; ++jt) {
    iv4 cav[2]; fv4 csv[2];
    cav[0] = pa0; cav[1] = pa1; csv[0] = pv0; csv[1] = pv1;
    if (jt + 1 < NIT) {
      const int o = (jt + 1) * 64;
      pa0 = __builtin_nontemporal_load((const iv4*)(adjRow + o));
      pa1 = __builtin_nontemporal_load((const iv4*)(adjRow + o + 4));
      pv0 = *(const fv4*)(s2p + o);
      pv1 = *(const fv4*)(s2p + o + 4);
    }

    alignas(16) unsigned short wv[8];
#pragma unroll
    for (int g = 0; g < 2; ++g) {
#pragma unroll
      for (int e = 0; e < 4; ++e) {
        float ee = s1r + csv[g][e];
        ee = ee >= 0.f ? ee : LRALPHA * ee;
        float w = __expf(ee - mr);
        w = cav[g][e] ? w : 0.f;
        const unsigned short u = f2bf(w);
        wv[g * 4 + e] = u;
        zloc += __uint_as_float((unsigned)u << 16);  // Z sums the bf16-rounded w
      }
    }
    *(uv4*)&P[r][cq * 8] = *(const uv4*)wv;
    __syncthreads();

    const size_t jbase = (size_t)(jlo + jt * 64);
#pragma unroll
    for (int kk = 0; kk < 2; ++kk) {
      frag_ab af[4];
#pragma unroll
      for (int mi = 0; mi < 4; ++mi)
        af[mi] = *(const frag_ab*)&P[mi * 16 + ln16][kk * 32 + quad * 8];
      frag_ab bf[2];
#pragma unroll
      for (int ni = 0; ni < 2; ++ni) {
        const int f = wave * 32 + ni * 16 + ln16;
        bf[ni] = *(const frag_ab*)(hT + (size_t)f * 8192 + jbase + kk * 32 + quad * 8);
      }
#pragma unroll
      for (int mi = 0; mi < 4; ++mi)
#pragma unroll
        for (int ni = 0; ni < 2; ++ni)
          acc[mi][ni] = __builtin_amdgcn_mfma_f32_16x16x32_bf16(
              af[mi], bf[ni], acc[mi][ni], 0, 0, 0);
    }
    __syncthreads();
  }

  // Z partial reduce (8 threads per row) + store
  Zred[r][cq] = zloc;
  __syncthreads();
  if (tid < 64) {
    float z = 0.f;
#pragma unroll
    for (int q = 0; q < 8; ++q) z += Zred[tid][q];
    pZ[ks * 8192 + row0 + tid] = z;
  }

  // store numerator partials (C/D layout: col=lane&15, row=quad*4+reg)
  float* paccb = pacc + ((size_t)ks * 8192 + row0) * 256;
#pragma unroll
  for (int mi = 0; mi < 4; ++mi) {
#pragma unroll
    for (int ni = 0; ni < 2; ++ni) {
      const int f = wave * 32 + ni * 16 + ln16;
#pragma unroll
      for (int reg = 0; reg < 4; ++reg) {
        const int grow = mi * 16 + quad * 4 + reg;
        __builtin_nontemporal_store(acc[mi][ni][reg], paccb + (size_t)grow * 256 + f);
      }
    }
  }
}

// ---------------- Kernel D: combine k-split partials, divide by Z, elu
__global__ __launch_bounds__(256) void gat_combine(
    const float* __restrict__ pacc, const float* __restrict__ pZ,
    float* __restrict__ out) {
  const int idx = blockIdx.x * 256 + threadIdx.x;  // float4 index, 524288 total
  const int row = idx >> 6;
  const float z = pZ[row] + pZ[8192 + row];
  const float invz = 1.f / z;
  const fv4 n0 = *(const fv4*)(pacc + (size_t)idx * 4);
  const fv4 n1 = *(const fv4*)(pacc + 2097152 + (size_t)idx * 4);
  fv4 o;
#pragma unroll
  for (int e = 0; e < 4; ++e) {
    const float v = (n0[e] + n1[e]) * invz;
    o[e] = v > 0.f ? v : expm1f(v);
  }
  *(fv4*)(out + (size_t)idx * 4) = o;
}

extern "C" void kernel_launch(void* const* d_in, const int* in_sizes, int n_in,
                              void* d_out, int out_size, void* d_ws, size_t ws_size,
                              hipStream_t stream) {
  const float* X = (const float*)d_in[0];
  const int* adj = (const int*)d_in[1];
  const float* W = (const float*)d_in[2];
  const float* avec = (const float*)d_in[3];
  float* out = (float*)d_out;

  float* wsf = (float*)d_ws;
  float* s1 = wsf;                        // 8192
  float* s2 = wsf + 8192;                 // 8192
  float* s2m = wsf + 16384;               // 1
  float* pZ = wsf + 24576;                // 2*8192
  float* pacc = wsf + 65536;              // 2*8192*256 = 4194304 floats (16 MB)
  unsigned short* hT = (unsigned short*)(wsf + 65536 + 4194304);  // 256*8192 bf16 (4 MB)

  hipLaunchKernelGGL(gat_hproj, dim3(512), dim3(256), 0, stream, X, W, avec, s1, s2, hT);
  hipLaunchKernelGGL(gat_s2max, dim3(1), dim3(256), 0, stream, s2, s2m);
  hipLaunchKernelGGL(gat_attn, dim3(256), dim3(512), 0, stream, adj, hT, s1, s2, s2m, pacc, pZ);
  hipLaunchKernelGGL(gat_combine, dim3(2048), dim3(256), 0, stream, pacc, pZ, out);
}

// Round 2
// 486.995 us; speedup vs baseline: 1.0289x; 1.0289x over previous
//
#include <hip/hip_runtime.h>
#include <hip/hip_bf16.h>

#define LRALPHA 0.2f

typedef __attribute__((ext_vector_type(8))) short frag_ab;   // 8 x bf16
typedef __attribute__((ext_vector_type(4))) float frag_cd;   // 4 x f32
typedef int   iv4 __attribute__((ext_vector_type(4)));
typedef float fv4 __attribute__((ext_vector_type(4)));
typedef unsigned int uv4 __attribute__((ext_vector_type(4)));

static __device__ __forceinline__ unsigned short f2bf(float f) {
  __hip_bfloat16 b = __float2bfloat16(f);
  unsigned short u;
  __builtin_memcpy(&u, &b, 2);
  return u;
}

// w >= 0, finite: fast RNE f32->bf16
static __device__ __forceinline__ uv4 make_w(const iv4* ca, const fv4* cv,
                                             float s1r, float mr, float& zloc) {
  alignas(16) unsigned short wv[8];
#pragma unroll
  for (int g = 0; g < 2; ++g) {
#pragma unroll
    for (int e = 0; e < 4; ++e) {
      float ee = s1r + cv[g][e];
      ee = fmaxf(ee, LRALPHA * ee);            // leakyrelu (slope<1)
      float w = __expf(ee - mr);
      w = ca[g][e] ? w : 0.f;
      unsigned b = __float_as_uint(w);
      b += 0x7FFFu + ((b >> 16) & 1u);         // RNE
      const unsigned short u = (unsigned short)(b >> 16);
      wv[g * 4 + e] = u;
      zloc += __uint_as_float((unsigned)u << 16);  // Z sums bf16-rounded w
    }
  }
  return *(const uv4*)wv;
}

// ---------------- Kernel A: h = X@W (fp32), s1/s2, hT = bf16(h)^T
// X rows read via wave-uniform addresses -> scalar (SMEM) loads, no LDS.
__global__ __launch_bounds__(256, 4) void gat_hproj(
    const float* __restrict__ X, const float* __restrict__ W,
    const float* __restrict__ avec,
    float* __restrict__ s1, float* __restrict__ s2,
    unsigned short* __restrict__ hT) {
  const int tid = threadIdx.x;
  const int row0 = blockIdx.x * 16;
  const float* Xb = X + (size_t)row0 * 256;
  const int c = tid;  // output column 0..255

  float acc[16];
#pragma unroll
  for (int r = 0; r < 16; ++r) acc[r] = 0.f;

  for (int k = 0; k < 256; k += 4) {
    const float w0 = W[(k + 0) * 256 + c];
    const float w1 = W[(k + 1) * 256 + c];
    const float w2 = W[(k + 2) * 256 + c];
    const float w3 = W[(k + 3) * 256 + c];
#pragma unroll
    for (int r = 0; r < 16; ++r) {
      acc[r] = fmaf(Xb[r * 256 + k + 0], w0, acc[r]);
      acc[r] = fmaf(Xb[r * 256 + k + 1], w1, acc[r]);
      acc[r] = fmaf(Xb[r * 256 + k + 2], w2, acc[r]);
      acc[r] = fmaf(Xb[r * 256 + k + 3], w3, acc[r]);
    }
  }

  // hT (bf16, [f][j] layout): thread writes 16 contiguous bf16 in row c
  alignas(16) unsigned short hu[16];
#pragma unroll
  for (int r = 0; r < 16; ++r) hu[r] = f2bf(acc[r]);
  uv4* hdst = (uv4*)(hT + (size_t)c * 8192 + row0);
  hdst[0] = *(const uv4*)&hu[0];
  hdst[1] = *(const uv4*)&hu[8];

  // s1/s2: reduce acc[r]*a over 256 threads (=columns)
  const float a1c = avec[c];
  const float a2c = avec[256 + c];
  const int lane = tid & 63, wave = tid >> 6;
  __shared__ float r1[4][16], r2[4][16];
#pragma unroll
  for (int r = 0; r < 16; ++r) {
    float v1 = acc[r] * a1c;
    float v2 = acc[r] * a2c;
#pragma unroll
    for (int off = 32; off > 0; off >>= 1) {
      v1 += __shfl_down(v1, off);
      v2 += __shfl_down(v2, off);
    }
    if (lane == 0) { r1[wave][r] = v1; r2[wave][r] = v2; }
  }
  __syncthreads();
  if (tid < 16) {
    s1[row0 + tid] = r1[0][tid] + r1[1][tid] + r1[2][tid] + r1[3][tid];
    s2[row0 + tid] = r2[0][tid] + r2[1][tid] + r2[2][tid] + r2[3][tid];
  }
}

// ---------------- Kernel B: global max of s2
__global__ void gat_s2max(const float* __restrict__ s2, float* __restrict__ s2max) {
  const int tid = threadIdx.x;
  float m = -1e30f;
  for (int i = tid; i < 8192; i += 256) m = fmaxf(m, s2[i]);
#pragma unroll
  for (int off = 32; off > 0; off >>= 1) m = fmaxf(m, __shfl_down(m, off));
  __shared__ float ws[4];
  if ((tid & 63) == 0) ws[tid >> 6] = m;
  __syncthreads();
  if (tid == 0) s2max[0] = fmaxf(fmaxf(ws[0], ws[1]), fmaxf(ws[2], ws[3]));
}

// ---------------- Kernel C: fused masked-softmax numerator + P@h (bf16 MFMA)
// 512 blocks x 512 threads; block = 64 rows x one j-quarter (2048 cols).
// Double-buffered P (one barrier/iter); w(jt+1) compute overlaps MFMA(jt);
// hT B-frags issued at iter top; adj prefetched 2 iters ahead (nontemporal).
__global__ __launch_bounds__(512, 4) void gat_attn(
    const int* __restrict__ adj, const unsigned short* __restrict__ hT,
    const float* __restrict__ s1, const float* __restrict__ s2,
    const float* __restrict__ s2maxp,
    float* __restrict__ pacc, float* __restrict__ pZ) {
  const int bid = blockIdx.x;
  const int x = bid & 7;                       // XCD slot
  const int ks = x >> 1;                       // j-quarter pinned to XCD pair
  const int rb = ((bid >> 3) << 1) | (x & 1);  // 0..127
  const int row0 = rb * 64;
  const int jlo = ks * 2048;
  const int tid = threadIdx.x;
  const int wave = tid >> 6, lane = tid & 63;
  const int ln16 = lane & 15, quad = lane >> 4;

  __shared__ __align__(16) unsigned short P[2][64][72];  // double-buffered, +8 pad
  __shared__ float Zred[64][8];

  const int r = tid >> 3, cq = tid & 7;  // 64 rows x 8 col-groups of 8
  const float s1r = s1[row0 + r];
  const float s2m = s2maxp[0];
  const float tmv = s1r + s2m;
  const float mr = tmv >= 0.f ? tmv : LRALPHA * tmv;  // lrelu(s1_i + max s2) >= row max

  const int* adjRow = adj + (size_t)(row0 + r) * 8192 + jlo + cq * 8;
  const float* s2p = s2 + jlo + cq * 8;

  frag_cd acc[4][2];
  const frag_cd fz = {0.f, 0.f, 0.f, 0.f};
#pragma unroll
  for (int mi = 0; mi < 4; ++mi)
#pragma unroll
    for (int ni = 0; ni < 2; ++ni) acc[mi][ni] = fz;

  float zloc = 0.f;
  const int NIT = 2048 / 64;  // 32

  // preamble: w(0) -> P[0]; prefetch adj/s2 for jt=1
  {
    iv4 ca[2]; fv4 cv[2];
    ca[0] = __builtin_nontemporal_load((const iv4*)(adjRow));
    ca[1] = __builtin_nontemporal_load((const iv4*)(adjRow + 4));
    cv[0] = *(const fv4*)(s2p);
    cv[1] = *(const fv4*)(s2p + 4);
    *(uv4*)&P[0][r][cq * 8] = make_w(ca, cv, s1r, mr, zloc);
  }
  iv4 a[2]; fv4 v[2];
  a[0] = __builtin_nontemporal_load((const iv4*)(adjRow + 64));
  a[1] = __builtin_nontemporal_load((const iv4*)(adjRow + 68));
  v[0] = *(const fv4*)(s2p + 64);
  v[1] = *(const fv4*)(s2p + 68);
  __syncthreads();

  for (int jt = 0; jt < NIT; ++jt) {
    const int cur = jt & 1, nxt = cur ^ 1;
    const size_t jbase = (size_t)(jlo + jt * 64);

    // B-fragments for THIS iter — issue first (L2 latency overlaps w-compute)
    frag_ab bf[2][2];  // [kk][ni]
#pragma unroll
    for (int kk = 0; kk < 2; ++kk)
#pragma unroll
      for (int ni = 0; ni < 2; ++ni) {
        const int f = wave * 32 + ni * 16 + ln16;
        bf[kk][ni] = *(const frag_ab*)(hT + (size_t)f * 8192 + jbase + kk * 32 + quad * 8);
      }

    // prefetch adj/s2 for jt+2
    iv4 a2[2]; fv4 v2[2];
    if (jt + 2 < NIT) {
      const int o = (jt + 2) * 64;
      a2[0] = __builtin_nontemporal_load((const iv4*)(adjRow + o));
      a2[1] = __builtin_nontemporal_load((const iv4*)(adjRow + o + 4));
      v2[0] = *(const fv4*)(s2p + o);
      v2[1] = *(const fv4*)(s2p + o + 4);
    }

    // compute w(jt+1) -> P[nxt] (overlaps MFMA of jt; barrier-safe: P[nxt]
    // was last read at jt-1, before the barrier we already passed)
    if (jt + 1 < NIT) {
      *(uv4*)&P[nxt][r][cq * 8] = make_w(a, v, s1r, mr, zloc);
    }

    // A-fragments from P[cur] + MFMA
#pragma unroll
    for (int kk = 0; kk < 2; ++kk) {
      frag_ab af[4];
#pragma unroll
      for (int mi = 0; mi < 4; ++mi)
        af[mi] = *(const frag_ab*)&P[cur][mi * 16 + ln16][kk * 32 + quad * 8];
#pragma unroll
      for (int mi = 0; mi < 4; ++mi)
#pragma unroll
        for (int ni = 0; ni < 2; ++ni)
          acc[mi][ni] = __builtin_amdgcn_mfma_f32_16x16x32_bf16(
              af[mi], bf[kk][ni], acc[mi][ni], 0, 0, 0);
    }
    __syncthreads();
    a[0] = a2[0]; a[1] = a2[1]; v[0] = v2[0]; v[1] = v2[1];
  }

  // Z partial reduce + store
  Zred[r][cq] = zloc;
  __syncthreads();
  if (tid < 64) {
    float z = 0.f;
#pragma unroll
    for (int q = 0; q < 8; ++q) z += Zred[tid][q];
    pZ[ks * 8192 + row0 + tid] = z;
  }

  // store numerator partials (C/D layout: col=lane&15, row=quad*4+reg)
  float* paccb = pacc + ((size_t)ks * 8192 + row0) * 256;
#pragma unroll
  for (int mi = 0; mi < 4; ++mi) {
#pragma unroll
    for (int ni = 0; ni < 2; ++ni) {
      const int f = wave * 32 + ni * 16 + ln16;
#pragma unroll
      for (int reg = 0; reg < 4; ++reg) {
        const int grow = mi * 16 + quad * 4 + reg;
        __builtin_nontemporal_store(acc[mi][ni][reg], paccb + (size_t)grow * 256 + f);
      }
    }
  }
}

// ---------------- Kernel D: combine 4 k-split partials, divide by Z, elu
__global__ __launch_bounds__(256) void gat_combine(
    const float* __restrict__ pacc, const float* __restrict__ pZ,
    float* __restrict__ out) {
  const int idx = blockIdx.x * 256 + threadIdx.x;  // float4 index, 524288 total
  const int row = idx >> 6;
  const float z = pZ[row] + pZ[8192 + row] + pZ[16384 + row] + pZ[24576 + row];
  const float invz = 1.f / z;
  const size_t PSTRIDE = (size_t)8192 * 256;  // floats per partial
  const fv4 n0 = *(const fv4*)(pacc + (size_t)idx * 4);
  const fv4 n1 = *(const fv4*)(pacc + PSTRIDE + (size_t)idx * 4);
  const fv4 n2 = *(const fv4*)(pacc + 2 * PSTRIDE + (size_t)idx * 4);
  const fv4 n3 = *(const fv4*)(pacc + 3 * PSTRIDE + (size_t)idx * 4);
  fv4 o;
#pragma unroll
  for (int e = 0; e < 4; ++e) {
    const float vsum = (n0[e] + n1[e]) + (n2[e] + n3[e]);
    const float vv = vsum * invz;
    o[e] = vv > 0.f ? vv : expm1f(vv);
  }
  *(fv4*)(out + (size_t)idx * 4) = o;
}

extern "C" void kernel_launch(void* const* d_in, const int* in_sizes, int n_in,
                              void* d_out, int out_size, void* d_ws, size_t ws_size,
                              hipStream_t stream) {
  const float* X = (const float*)d_in[0];
  const int* adj = (const int*)d_in[1];
  const float* W = (const float*)d_in[2];
  const float* avec = (const float*)d_in[3];
  float* out = (float*)d_out;

  float* wsf = (float*)d_ws;
  float* s1 = wsf;                        // 8192
  float* s2 = wsf + 8192;                 // 8192
  float* s2m = wsf + 16384;               // 1
  float* pZ = wsf + 24576;                // 4*8192
  float* pacc = wsf + 65536;              // 4*8192*256 floats (32 MB)
  unsigned short* hT = (unsigned short*)(wsf + 65536 + 4 * 8192 * 256);  // 4 MB

  hipLaunchKernelGGL(gat_hproj, dim3(512), dim3(256), 0, stream, X, W, avec, s1, s2, hT);
  hipLaunchKernelGGL(gat_s2max, dim3(1), dim3(256), 0, stream, s2, s2m);
  hipLaunchKernelGGL(gat_attn, dim3(512), dim3(512), 0, stream, adj, hT, s1, s2, s2m, pacc, pZ);
  hipLaunchKernelGGL(gat_combine, dim3(2048), dim3(256), 0, stream, pacc, pZ, out);
}